// Round 1
// baseline (147.770 us; speedup 1.0000x reference)
//
#include <hip/hip_runtime.h>
#include <hip/hip_bf16.h>
#include <stdint.h>

typedef __bf16 bf16x8 __attribute__((ext_vector_type(8)));
typedef float f32x4 __attribute__((ext_vector_type(4)));

constexpr int IN_F = 1024;
constexpr int OUT_F = 1024;
constexpr int M_TOT = 8 * 4096;   // 32768 tokens
constexpr int K_TOT = IN_F;
constexpr int N_TOT = OUT_F;

static __device__ __forceinline__ uint16_t f32_bits_to_bf16(float f) {
    // exact for integers in [-128,127] (<=8 significant bits): low 16 bits are zero
    return (uint16_t)(__builtin_bit_cast(uint32_t, f) >> 16);
}

// ---------------- kernel 1: per-token int8 fake-quant -> bf16 q ----------------
__global__ __launch_bounds__(256) void quant_kernel(
    const float* __restrict__ x,
    const float* __restrict__ wscale,
    uint16_t* __restrict__ q,          // [M_TOT][K_TOT] bf16 bits
    float* __restrict__ inv_row)       // [M_TOT]  (= a/127 * weight_scale)
{
    const int row = blockIdx.x;
    const int t = threadIdx.x;
    const float4 v = reinterpret_cast<const float4*>(x + (size_t)row * IN_F)[t];
    float m = fmaxf(fmaxf(fabsf(v.x), fabsf(v.y)), fmaxf(fabsf(v.z), fabsf(v.w)));
    #pragma unroll
    for (int off = 32; off > 0; off >>= 1)
        m = fmaxf(m, __shfl_xor(m, off));
    __shared__ float smax[4];
    if ((t & 63) == 0) smax[t >> 6] = m;
    __syncthreads();
    m = fmaxf(fmaxf(smax[0], smax[1]), fmaxf(smax[2], smax[3]));
    const float a = fmaxf(m, 1e-5f);
    const float as = 127.0f / a;

    ushort4 o;
    float q0 = fminf(fmaxf(rintf(v.x * as), -128.0f), 127.0f);
    float q1 = fminf(fmaxf(rintf(v.y * as), -128.0f), 127.0f);
    float q2 = fminf(fmaxf(rintf(v.z * as), -128.0f), 127.0f);
    float q3 = fminf(fmaxf(rintf(v.w * as), -128.0f), 127.0f);
    o.x = f32_bits_to_bf16(q0);
    o.y = f32_bits_to_bf16(q1);
    o.z = f32_bits_to_bf16(q2);
    o.w = f32_bits_to_bf16(q3);
    reinterpret_cast<ushort4*>(q + (size_t)row * IN_F)[t] = o;
    if (t == 0) inv_row[row] = (a / 127.0f) * wscale[0];
}

// ---------------- kernel 2: unpack ternary weights (bit-plane permuted) ----------------
// reference: w_flat[i] = ((packed[i & 262143] >> (2*(i>>18))) & 3) - 1
// with i = o*1024 + k  ->  shift plane s = o>>8 (constant per o), p = (o&255)*1024 + k
__global__ __launch_bounds__(256) void unpack_kernel(
    const int* __restrict__ packed,
    uint16_t* __restrict__ wt)         // [OUT_F][IN_F] bf16 bits (B^T layout)
{
    const int o = blockIdx.x;
    const int k0 = threadIdx.x * 4;
    const int sh = (o >> 8) * 2;
    const int pbase = ((o & 255) << 10) + k0;
    const int4 pw = *reinterpret_cast<const int4*>(packed + pbase);
    ushort4 r;
    {
        int e;
        e = (pw.x >> sh) & 3; r.x = (e == 0) ? 0xBF80u : ((e == 2) ? 0x3F80u : 0u);
        e = (pw.y >> sh) & 3; r.y = (e == 0) ? 0xBF80u : ((e == 2) ? 0x3F80u : 0u);
        e = (pw.z >> sh) & 3; r.z = (e == 0) ? 0xBF80u : ((e == 2) ? 0x3F80u : 0u);
        e = (pw.w >> sh) & 3; r.w = (e == 0) ? 0xBF80u : ((e == 2) ? 0x3F80u : 0u);
    }
    *reinterpret_cast<ushort4*>(wt + (size_t)o * IN_F + k0) = r;
}

// ---------------- kernel 3: bf16 MFMA GEMM, C[m][n] = sum_k q[m][k]*t[n][k] ----------------
constexpr int BM = 128, BN = 128, BK = 64;

__global__ __launch_bounds__(256) void gemm_kernel(
    const uint16_t* __restrict__ qa,    // [M_TOT][K_TOT] bf16 bits
    const uint16_t* __restrict__ wb,    // [N_TOT][K_TOT] bf16 bits
    const float* __restrict__ inv_row,  // [M_TOT] (includes weight_scale)
    const float* __restrict__ bias,     // [N_TOT]
    float* __restrict__ out)            // [M_TOT][N_TOT]
{
    // XCD-aware swizzle: nwg = 2048, divisible by 8 -> simple bijective remap
    const int nwg = gridDim.x;
    const int cpx = nwg >> 3;
    int bid = blockIdx.x;
    bid = (bid & 7) * cpx + (bid >> 3);
    const int ntn = N_TOT / BN;                 // 8
    const int tm = bid / ntn;
    const int tn = bid % ntn;

    const int tid = threadIdx.x;
    const int lane = tid & 63;
    const int wid = tid >> 6;                   // 0..3
    const int wr = wid >> 1;                    // wave row 0..1
    const int wc = wid & 1;                     // wave col 0..1

    __shared__ uint16_t lA[BM * BK];            // 16 KiB
    __shared__ uint16_t lB[BN * BK];            // 16 KiB

    f32x4 acc[4][4] = {};

    const int rowA0 = tm * BM;
    const int rowB0 = tn * BN;

    // staging: chunk c = j*256 + tid covers 16 B; row = c>>3, col = (c&7)*8 (bf16 elems)
    const int c_row = tid >> 3;                 // + j*32
    const int c_col = (tid & 7) * 8;

    const int fr_row = lane & 15;
    const int fr_k0 = (lane >> 4) * 8;          // 0,8,16,24

    for (int kt = 0; kt < K_TOT / BK; ++kt) {
        const int kbase = kt * BK;
        #pragma unroll
        for (int j = 0; j < 4; ++j) {
            const int r = c_row + j * 32;
            const uint16_t* gA = qa + (size_t)(rowA0 + r) * K_TOT + kbase + c_col;
            const uint16_t* gB = wb + (size_t)(rowB0 + r) * K_TOT + kbase + c_col;
            __builtin_amdgcn_global_load_lds(
                (const __attribute__((address_space(1))) void*)gA,
                (__attribute__((address_space(3))) void*)&lA[r * BK + c_col], 16, 0, 0);
            __builtin_amdgcn_global_load_lds(
                (const __attribute__((address_space(1))) void*)gB,
                (__attribute__((address_space(3))) void*)&lB[r * BK + c_col], 16, 0, 0);
        }
        __syncthreads();

        #pragma unroll
        for (int kk = 0; kk < 2; ++kk) {
            bf16x8 af[4], bfr[4];
            #pragma unroll
            for (int m = 0; m < 4; ++m) {
                const int row = wr * 64 + m * 16 + fr_row;
                af[m] = *reinterpret_cast<const bf16x8*>(&lA[row * BK + kk * 32 + fr_k0]);
            }
            #pragma unroll
            for (int n = 0; n < 4; ++n) {
                const int row = wc * 64 + n * 16 + fr_row;
                bfr[n] = *reinterpret_cast<const bf16x8*>(&lB[row * BK + kk * 32 + fr_k0]);
            }
            #pragma unroll
            for (int m = 0; m < 4; ++m)
                #pragma unroll
                for (int n = 0; n < 4; ++n)
                    acc[m][n] = __builtin_amdgcn_mfma_f32_16x16x32_bf16(af[m], bfr[n], acc[m][n], 0, 0, 0);
        }
        __syncthreads();
    }

    // epilogue: C/D layout for 16x16: col = lane&15, row = (lane>>4)*4 + reg
    const int orow_base = rowA0 + wr * 64 + (lane >> 4) * 4;
    const int ocol_base = rowB0 + wc * 64 + (lane & 15);
    #pragma unroll
    for (int m = 0; m < 4; ++m) {
        #pragma unroll
        for (int j = 0; j < 4; ++j) {
            const int gm = orow_base + m * 16 + j;
            const float sc = inv_row[gm];
            #pragma unroll
            for (int n = 0; n < 4; ++n) {
                const int gn = ocol_base + n * 16;
                out[(size_t)gm * N_TOT + gn] = acc[m][n][j] * sc + bias[gn];
            }
        }
    }
}

extern "C" void kernel_launch(void* const* d_in, const int* in_sizes, int n_in,
                              void* d_out, int out_size, void* d_ws, size_t ws_size,
                              hipStream_t stream) {
    const float* x = (const float*)d_in[0];
    const int* packed = (const int*)d_in[1];
    const float* wscale = (const float*)d_in[2];
    const float* bias = (const float*)d_in[3];
    float* out = (float*)d_out;

    // workspace layout
    uint16_t* q = (uint16_t*)d_ws;                                    // 64 MiB
    uint16_t* wt = (uint16_t*)((char*)d_ws + (size_t)M_TOT * K_TOT * 2);   // 2 MiB
    float* inv_row = (float*)((char*)d_ws + (size_t)M_TOT * K_TOT * 2 + (size_t)N_TOT * K_TOT * 2);

    quant_kernel<<<M_TOT, 256, 0, stream>>>(x, wscale, q, inv_row);
    unpack_kernel<<<OUT_F, 256, 0, stream>>>(packed, wt);
    gemm_kernel<<<(M_TOT / BM) * (N_TOT / BN), 256, 0, stream>>>(q, wt, inv_row, bias, out);
}

// Round 2
// 123.771 us; speedup vs baseline: 1.1939x; 1.1939x over previous
//
#include <hip/hip_runtime.h>
#include <hip/hip_bf16.h>
#include <stdint.h>

typedef __bf16 bf16x8 __attribute__((ext_vector_type(8)));
typedef float f32x4 __attribute__((ext_vector_type(4)));

constexpr int IN_F = 1024;
constexpr int OUT_F = 1024;
constexpr int M_TOT = 8 * 4096;   // 32768 tokens
constexpr int K_TOT = IN_F;
constexpr int N_TOT = OUT_F;

static __device__ __forceinline__ uint16_t f32_bits_to_bf16(float f) {
    // exact for integers in [-128,127]
    return (uint16_t)(__builtin_bit_cast(uint32_t, f) >> 16);
}

// ---------------- kernel 1: per-token int8 fake-quant -> bf16 q ----------------
__global__ __launch_bounds__(256) void quant_kernel(
    const float* __restrict__ x,
    const float* __restrict__ wscale,
    uint16_t* __restrict__ q,          // [M_TOT][K_TOT] bf16 bits
    float* __restrict__ inv_row)       // [M_TOT]  (= a/127 * weight_scale)
{
    const int row = blockIdx.x;
    const int t = threadIdx.x;
    const float4 v = reinterpret_cast<const float4*>(x + (size_t)row * IN_F)[t];
    float m = fmaxf(fmaxf(fabsf(v.x), fabsf(v.y)), fmaxf(fabsf(v.z), fabsf(v.w)));
    #pragma unroll
    for (int off = 32; off > 0; off >>= 1)
        m = fmaxf(m, __shfl_xor(m, off));
    __shared__ float smax[4];
    if ((t & 63) == 0) smax[t >> 6] = m;
    __syncthreads();
    m = fmaxf(fmaxf(smax[0], smax[1]), fmaxf(smax[2], smax[3]));
    const float a = fmaxf(m, 1e-5f);
    const float as = 127.0f / a;

    ushort4 o;
    o.x = f32_bits_to_bf16(fminf(fmaxf(rintf(v.x * as), -128.0f), 127.0f));
    o.y = f32_bits_to_bf16(fminf(fmaxf(rintf(v.y * as), -128.0f), 127.0f));
    o.z = f32_bits_to_bf16(fminf(fmaxf(rintf(v.z * as), -128.0f), 127.0f));
    o.w = f32_bits_to_bf16(fminf(fmaxf(rintf(v.w * as), -128.0f), 127.0f));
    reinterpret_cast<ushort4*>(q + (size_t)row * IN_F)[t] = o;
    if (t == 0) inv_row[row] = (a / 127.0f) * wscale[0];
}

// ---------------- kernel 2: unpack ternary weights (bit-plane permuted) ----------------
__global__ __launch_bounds__(256) void unpack_kernel(
    const int* __restrict__ packed,
    uint16_t* __restrict__ wt)         // [OUT_F][IN_F] bf16 bits (B^T layout)
{
    const int o = blockIdx.x;
    const int k0 = threadIdx.x * 4;
    const int sh = (o >> 8) * 2;
    const int pbase = ((o & 255) << 10) + k0;
    const int4 pw = *reinterpret_cast<const int4*>(packed + pbase);
    ushort4 r;
    {
        int e;
        e = (pw.x >> sh) & 3; r.x = (e == 0) ? 0xBF80u : ((e == 2) ? 0x3F80u : 0u);
        e = (pw.y >> sh) & 3; r.y = (e == 0) ? 0xBF80u : ((e == 2) ? 0x3F80u : 0u);
        e = (pw.z >> sh) & 3; r.z = (e == 0) ? 0xBF80u : ((e == 2) ? 0x3F80u : 0u);
        e = (pw.w >> sh) & 3; r.w = (e == 0) ? 0xBF80u : ((e == 2) ? 0x3F80u : 0u);
    }
    *reinterpret_cast<ushort4*>(wt + (size_t)o * IN_F + k0) = r;
}

// ---------------- kernel 3: pipelined bf16 MFMA GEMM ----------------
// BM=256 x BN=128 tile, BK=64, 8 waves (4 M x 2 N), per-wave 64x64 output.
// 3 LDS buffers (144 KiB): 2-tile lookahead; counted vmcnt(6), never 0 in loop.
// T2 swizzle: linear LDS dest (global_load_lds), inverse-swizzled global src,
// swizzled ds_read (chunk ^= row&7) -- same involution both sides.
constexpr int BM = 256, BN = 128, BK = 64, NBUF = 3;
constexpr int NT = K_TOT / BK;   // 16

__global__ __launch_bounds__(512) void gemm_kernel(
    const uint16_t* __restrict__ qa,    // [M_TOT][K_TOT] bf16 bits
    const uint16_t* __restrict__ wb,    // [N_TOT][K_TOT] bf16 bits
    const float* __restrict__ inv_row,
    const float* __restrict__ bias,
    float* __restrict__ out)
{
    // XCD-aware swizzle: nwg = 1024, divisible by 8 -> bijective simple remap
    int bid = blockIdx.x;
    bid = (bid & 7) * ((int)gridDim.x >> 3) + (bid >> 3);
    const int tm = bid >> 3;            // 0..127
    const int tn = bid & 7;             // 0..7

    const int tid = threadIdx.x;
    const int lane = tid & 63;
    const int wid = tid >> 6;           // 0..7
    const int wr = wid >> 1;            // 0..3 (M)
    const int wc = wid & 1;             // 0..1 (N)

    __shared__ uint16_t lA[NBUF][BM * BK];   // 3 x 32 KiB
    __shared__ uint16_t lB[NBUF][BN * BK];   // 3 x 16 KiB

    const int rowA0 = tm * BM;
    const int rowB0 = tn * BN;

    const int frow = lane & 15;
    const int fq = lane >> 4;           // 0..3

    f32x4 acc[4][4] = {};

    // --- staging: chunk c = j*512 + tid covers 16B; r = c>>3, chunk-in-row cc = c&7.
    // LDS dest is LINEAR (chunk c at byte c*16); global src chunk is cc ^ (r&7).
    auto stageA = [&](int buf, int kt, int j) {
        const int c = j * 512 + tid;
        const int r = c >> 3, cc = c & 7;
        const int scc = cc ^ (r & 7);
        const uint16_t* src = qa + (size_t)(rowA0 + r) * K_TOT + kt * BK + scc * 8;
        __builtin_amdgcn_global_load_lds(
            (const __attribute__((address_space(1))) void*)src,
            (__attribute__((address_space(3))) void*)&lA[buf][c * 8], 16, 0, 0);
    };
    auto stageB = [&](int buf, int kt, int j) {
        const int c = j * 512 + tid;
        const int r = c >> 3, cc = c & 7;
        const int scc = cc ^ (r & 7);
        const uint16_t* src = wb + (size_t)(rowB0 + r) * K_TOT + kt * BK + scc * 8;
        __builtin_amdgcn_global_load_lds(
            (const __attribute__((address_space(1))) void*)src,
            (__attribute__((address_space(3))) void*)&lB[buf][c * 8], 16, 0, 0);
    };

    // prologue: tiles 0 and 1 (6 loads each)
    #pragma unroll
    for (int j = 0; j < 4; ++j) stageA(0, 0, j);
    #pragma unroll
    for (int j = 0; j < 2; ++j) stageB(0, 0, j);
    #pragma unroll
    for (int j = 0; j < 4; ++j) stageA(1, 1, j);
    #pragma unroll
    for (int j = 0; j < 2; ++j) stageB(1, 1, j);

    for (int t = 0; t < NT; ++t) {
        const int cur = t % 3;
        const int nb = (t + 2) % 3;      // buffer freed at end of iter t-1
        const bool doStage = (t + 2) < NT;

        // wait: tile t's 6 loads landed (tile t+1's 6 may stay in flight)
        if (t < NT - 1) asm volatile("s_waitcnt vmcnt(6)" ::: "memory");
        else            asm volatile("s_waitcnt vmcnt(0)" ::: "memory");
        __builtin_amdgcn_s_barrier();

        #pragma unroll
        for (int kk = 0; kk < 2; ++kk) {
            bf16x8 af[4], bf[4];
            #pragma unroll
            for (int mf = 0; mf < 4; ++mf) {
                const int row = wr * 64 + mf * 16 + frow;
                const int ck = kk * 4 + fq;
                af[mf] = *reinterpret_cast<const bf16x8*>(
                    &lA[cur][(row * 8 + (ck ^ (row & 7))) * 8]);
            }
            #pragma unroll
            for (int nf = 0; nf < 4; ++nf) {
                const int row = wc * 64 + nf * 16 + frow;
                const int ck = kk * 4 + fq;
                bf[nf] = *reinterpret_cast<const bf16x8*>(
                    &lB[cur][(row * 8 + (ck ^ (row & 7))) * 8]);
            }
            // issue 3 of tile t+2's loads per phase (6 total/iter)
            if (doStage) {
                if (kk == 0) { stageA(nb, t + 2, 0); stageA(nb, t + 2, 1); stageB(nb, t + 2, 0); }
                else         { stageA(nb, t + 2, 2); stageA(nb, t + 2, 3); stageB(nb, t + 2, 1); }
            }
            __builtin_amdgcn_s_barrier();
            asm volatile("s_waitcnt lgkmcnt(0)" ::: "memory");
            __builtin_amdgcn_sched_barrier(0);
            __builtin_amdgcn_s_setprio(1);
            #pragma unroll
            for (int mf = 0; mf < 4; ++mf)
                #pragma unroll
                for (int nf = 0; nf < 4; ++nf)
                    acc[mf][nf] = __builtin_amdgcn_mfma_f32_16x16x32_bf16(
                        af[mf], bf[nf], acc[mf][nf], 0, 0, 0);
            __builtin_amdgcn_s_setprio(0);
            if (kk == 0) __builtin_amdgcn_s_barrier();
            // kk==1: loop wraps to the top barrier
        }
    }

    // epilogue: C/D 16x16 layout: col = lane&15, row = fq*4 + reg
    const int orow = rowA0 + wr * 64 + fq * 4;
    const int ocol = rowB0 + wc * 64 + frow;
    #pragma unroll
    for (int mf = 0; mf < 4; ++mf) {
        #pragma unroll
        for (int j = 0; j < 4; ++j) {
            const int gm = orow + mf * 16 + j;
            const float sc = inv_row[gm];
            #pragma unroll
            for (int nf = 0; nf < 4; ++nf) {
                const int gn = ocol + nf * 16;
                out[(size_t)gm * N_TOT + gn] = acc[mf][nf][j] * sc + bias[gn];
            }
        }
    }
}

extern "C" void kernel_launch(void* const* d_in, const int* in_sizes, int n_in,
                              void* d_out, int out_size, void* d_ws, size_t ws_size,
                              hipStream_t stream) {
    const float* x = (const float*)d_in[0];
    const int* packed = (const int*)d_in[1];
    const float* wscale = (const float*)d_in[2];
    const float* bias = (const float*)d_in[3];
    float* out = (float*)d_out;

    uint16_t* q = (uint16_t*)d_ws;                                         // 64 MiB
    uint16_t* wt = (uint16_t*)((char*)d_ws + (size_t)M_TOT * K_TOT * 2);   // 2 MiB
    float* inv_row = (float*)((char*)d_ws + (size_t)M_TOT * K_TOT * 2 + (size_t)N_TOT * K_TOT * 2);

    quant_kernel<<<M_TOT, 256, 0, stream>>>(x, wscale, q, inv_row);
    unpack_kernel<<<OUT_F, 256, 0, stream>>>(packed, wt);
    gemm_kernel<<<(M_TOT / BM) * (N_TOT / BN), 512, 0, stream>>>(q, wt, inv_row, bias, out);
}

// Round 4
// 113.994 us; speedup vs baseline: 1.2963x; 1.0858x over previous
//
#include <hip/hip_runtime.h>
#include <hip/hip_bf16.h>
#include <stdint.h>

typedef __bf16 bf16x8 __attribute__((ext_vector_type(8)));
typedef float f32x4 __attribute__((ext_vector_type(4)));

constexpr int IN_F = 1024;
constexpr int OUT_F = 1024;
constexpr int M_TOT = 8 * 4096;   // 32768 tokens
constexpr int K_TOT = IN_F;
constexpr int N_TOT = OUT_F;

static __device__ __forceinline__ uint16_t f32_bits_to_bf16(float f) {
    // exact for integers in [-128,127]
    return (uint16_t)(__builtin_bit_cast(uint32_t, f) >> 16);
}

// ---------------- kernel 1: per-token int8 fake-quant -> bf16 q ----------------
__global__ __launch_bounds__(256) void quant_kernel(
    const float* __restrict__ x,
    const float* __restrict__ wscale,
    uint16_t* __restrict__ q,          // [M_TOT][K_TOT] bf16 bits
    float* __restrict__ inv_row)       // [M_TOT]  (= a/127 * weight_scale)
{
    const int row = blockIdx.x;
    const int t = threadIdx.x;
    const float4 v = reinterpret_cast<const float4*>(x + (size_t)row * IN_F)[t];
    float m = fmaxf(fmaxf(fabsf(v.x), fabsf(v.y)), fmaxf(fabsf(v.z), fabsf(v.w)));
    #pragma unroll
    for (int off = 32; off > 0; off >>= 1)
        m = fmaxf(m, __shfl_xor(m, off));
    __shared__ float smax[4];
    if ((t & 63) == 0) smax[t >> 6] = m;
    __syncthreads();
    m = fmaxf(fmaxf(smax[0], smax[1]), fmaxf(smax[2], smax[3]));
    const float a = fmaxf(m, 1e-5f);
    const float as = 127.0f / a;

    ushort4 o;
    o.x = f32_bits_to_bf16(fminf(fmaxf(rintf(v.x * as), -128.0f), 127.0f));
    o.y = f32_bits_to_bf16(fminf(fmaxf(rintf(v.y * as), -128.0f), 127.0f));
    o.z = f32_bits_to_bf16(fminf(fmaxf(rintf(v.z * as), -128.0f), 127.0f));
    o.w = f32_bits_to_bf16(fminf(fmaxf(rintf(v.w * as), -128.0f), 127.0f));
    reinterpret_cast<ushort4*>(q + (size_t)row * IN_F)[t] = o;
    if (t == 0) inv_row[row] = (a / 127.0f) * wscale[0];
}

// ---------------- kernel 2: unpack ternary weights (bit-plane permuted) ----------------
__global__ __launch_bounds__(256) void unpack_kernel(
    const int* __restrict__ packed,
    uint16_t* __restrict__ wt)         // [OUT_F][IN_F] bf16 bits (B^T layout)
{
    const int o = blockIdx.x;
    const int k0 = threadIdx.x * 4;
    const int sh = (o >> 8) * 2;
    const int pbase = ((o & 255) << 10) + k0;
    const int4 pw = *reinterpret_cast<const int4*>(packed + pbase);
    ushort4 r;
    {
        int e;
        e = (pw.x >> sh) & 3; r.x = (e == 0) ? 0xBF80u : ((e == 2) ? 0x3F80u : 0u);
        e = (pw.y >> sh) & 3; r.y = (e == 0) ? 0xBF80u : ((e == 2) ? 0x3F80u : 0u);
        e = (pw.z >> sh) & 3; r.z = (e == 0) ? 0xBF80u : ((e == 2) ? 0x3F80u : 0u);
        e = (pw.w >> sh) & 3; r.w = (e == 0) ? 0xBF80u : ((e == 2) ? 0x3F80u : 0u);
    }
    *reinterpret_cast<ushort4*>(wt + (size_t)o * IN_F + k0) = r;
}

// ---------------- kernel 3: 256x256 4-phase/K-tile pipelined bf16 MFMA GEMM ----------------
// BM=BN=256, BK=64. 8 waves (2M x 4N), per-wave 128x64 output, register-held frags:
// 24 ds_read_b128 per 64 MFMA per K-tile. LDS 128 KiB = [buf2][ab2][half2][128x64].
// Staggered staging: 1 half-tile (2 global_load_lds) per phase, region re-staged only
// >=1 barrier after its previous reads finish (B halves free after P1, A after P2).
// Counted vmcnt(4) once per K-tile; never 0 mid-loop.
// T2 swizzle: linear LDS dest, inverse-swizzled global src, swizzled ds_read.
constexpr int BM = 256, BN = 256, BK = 64;
constexpr int NT = K_TOT / BK;   // 16

__global__ __launch_bounds__(512) void gemm_kernel(
    const uint16_t* __restrict__ qa,    // [M_TOT][K_TOT] bf16 bits
    const uint16_t* __restrict__ wb,    // [N_TOT][K_TOT] bf16 bits
    const float* __restrict__ inv_row,
    const float* __restrict__ bias,
    float* __restrict__ out)
{
    // XCD-aware swizzle: nwg = 512, divisible by 8 -> bijective simple remap
    int bid = blockIdx.x;
    bid = (bid & 7) * ((int)gridDim.x >> 3) + (bid >> 3);
    const int tm = bid >> 2;            // 0..127
    const int tn = bid & 3;             // 0..3

    const int tid = threadIdx.x;
    const int lane = tid & 63;
    const int wid = tid >> 6;           // 0..7
    const int wr = wid >> 2;            // 0..1 (M half: rows wr*128..)
    const int wc = wid & 3;             // 0..3 (N quarter: cols wc*64..)

    __shared__ uint16_t lds[2][2][2][128 * 64];  // [buf][ab][half] 16KiB regions = 128 KiB

    const int rowA0 = tm * BM;
    const int rowB0 = tn * BN;
    const int frow = lane & 15;
    const int fq = lane >> 4;           // 0..3

    f32x4 acc[8][4] = {};               // [ (q<<2)|mf ][ (qn<<1)|nf ]

    // stage one half-tile region (128 rows x 64 cols): 2 global_load_lds per thread
    auto stage = [&](int buf, int ab, int half, int kt) {
        const uint16_t* base = ab ? wb : qa;
        const int row0 = (ab ? rowB0 : rowA0) + half * 128;
        #pragma unroll
        for (int j = 0; j < 2; ++j) {
            const int c = j * 512 + tid;          // chunk 0..1023 (16B each)
            const int r = c >> 3, cc = c & 7;
            const int scc = cc ^ (r & 7);         // inverse swizzle on global src
            const uint16_t* src = base + (size_t)(row0 + r) * K_TOT + kt * BK + scc * 8;
            __builtin_amdgcn_global_load_lds(
                (const __attribute__((address_space(1))) void*)src,
                (__attribute__((address_space(3))) void*)&lds[buf][ab][half][c * 8],
                16, 0, 0);
        }
    };

    auto ldfrag = [&](int buf, int ab, int half, int row, int ck) -> bf16x8 {
        return *reinterpret_cast<const bf16x8*>(
            &lds[buf][ab][half][(row * 8 + (ck ^ (row & 7))) * 8]);
    };

    // prologue: stage tile0 {B-h0,A-h0,B-h1,A-h1}, tile1 {B-h0,A-h0}  (12 loads)
    stage(0, 1, 0, 0); stage(0, 0, 0, 0); stage(0, 1, 1, 0); stage(0, 0, 1, 0);
    stage(1, 1, 0, 1); stage(1, 0, 0, 1);
    asm volatile("s_waitcnt vmcnt(4)" ::: "memory");   // tile0 landed; tile1 B/A-h0 in flight
    __builtin_amdgcn_s_barrier();

    for (int T = 0; T < NT; ++T) {
        const int c = T & 1;
        bf16x8 aF[4][2], bF0[2][2], bF1[2][2];

        // ---- P0: read A rows 0-63 (8) + B cols 0-31 (4); stage B-h1(T+1); MFMA (0,0)
        #pragma unroll
        for (int mf = 0; mf < 4; ++mf)
            #pragma unroll
            for (int kk = 0; kk < 2; ++kk)
                aF[mf][kk] = ldfrag(c, 0, wr, mf * 16 + frow, kk * 4 + fq);
        #pragma unroll
        for (int nf = 0; nf < 2; ++nf)
            #pragma unroll
            for (int kk = 0; kk < 2; ++kk)
                bF0[nf][kk] = ldfrag(c, 1, wc >> 1, (wc & 1) * 64 + nf * 16 + frow, kk * 4 + fq);
        if (T + 1 < NT) stage((T + 1) & 1, 1, 1, T + 1);
        __builtin_amdgcn_s_barrier();
        asm volatile("s_waitcnt lgkmcnt(0)" ::: "memory");
        __builtin_amdgcn_sched_barrier(0);
        __builtin_amdgcn_s_setprio(1);
        #pragma unroll
        for (int mf = 0; mf < 4; ++mf)
            #pragma unroll
            for (int nf = 0; nf < 2; ++nf)
                #pragma unroll
                for (int kk = 0; kk < 2; ++kk)
                    acc[mf][nf] = __builtin_amdgcn_mfma_f32_16x16x32_bf16(
                        aF[mf][kk], bF0[nf][kk], acc[mf][nf], 0, 0, 0);
        __builtin_amdgcn_s_setprio(0);
        __builtin_amdgcn_s_barrier();

        // ---- P1: read B cols 32-63 (4); stage A-h1(T+1); MFMA (0,1)
        #pragma unroll
        for (int nf = 0; nf < 2; ++nf)
            #pragma unroll
            for (int kk = 0; kk < 2; ++kk)
                bF1[nf][kk] = ldfrag(c, 1, wc >> 1, (wc & 1) * 64 + 32 + nf * 16 + frow, kk * 4 + fq);
        if (T + 1 < NT) stage((T + 1) & 1, 0, 1, T + 1);
        __builtin_amdgcn_s_barrier();
        asm volatile("s_waitcnt lgkmcnt(0)" ::: "memory");
        __builtin_amdgcn_sched_barrier(0);
        __builtin_amdgcn_s_setprio(1);
        #pragma unroll
        for (int mf = 0; mf < 4; ++mf)
            #pragma unroll
            for (int nf = 0; nf < 2; ++nf)
                #pragma unroll
                for (int kk = 0; kk < 2; ++kk)
                    acc[mf][2 + nf] = __builtin_amdgcn_mfma_f32_16x16x32_bf16(
                        aF[mf][kk], bF1[nf][kk], acc[mf][2 + nf], 0, 0, 0);
        __builtin_amdgcn_s_setprio(0);
        __builtin_amdgcn_s_barrier();

        // ---- P2: read A rows 64-127 (8); stage B-h0(T+2); MFMA (1,1)
        #pragma unroll
        for (int mf = 0; mf < 4; ++mf)
            #pragma unroll
            for (int kk = 0; kk < 2; ++kk)
                aF[mf][kk] = ldfrag(c, 0, wr, 64 + mf * 16 + frow, kk * 4 + fq);
        if (T + 2 < NT) stage(T & 1, 1, 0, T + 2);
        __builtin_amdgcn_s_barrier();
        asm volatile("s_waitcnt lgkmcnt(0)" ::: "memory");
        __builtin_amdgcn_sched_barrier(0);
        __builtin_amdgcn_s_setprio(1);
        #pragma unroll
        for (int mf = 0; mf < 4; ++mf)
            #pragma unroll
            for (int nf = 0; nf < 2; ++nf)
                #pragma unroll
                for (int kk = 0; kk < 2; ++kk)
                    acc[4 + mf][2 + nf] = __builtin_amdgcn_mfma_f32_16x16x32_bf16(
                        aF[mf][kk], bF1[nf][kk], acc[4 + mf][2 + nf], 0, 0, 0);
        __builtin_amdgcn_s_setprio(0);
        __builtin_amdgcn_s_barrier();

        // ---- P3: no reads; stage A-h0(T+2); MFMA (1,0); counted vmcnt + barrier
        if (T + 2 < NT) stage(T & 1, 0, 0, T + 2);
        __builtin_amdgcn_s_setprio(1);
        #pragma unroll
        for (int mf = 0; mf < 4; ++mf)
            #pragma unroll
            for (int nf = 0; nf < 2; ++nf)
                #pragma unroll
                for (int kk = 0; kk < 2; ++kk)
                    acc[4 + mf][nf] = __builtin_amdgcn_mfma_f32_16x16x32_bf16(
                        aF[mf][kk], bF0[nf][kk], acc[4 + mf][nf], 0, 0, 0);
        __builtin_amdgcn_s_setprio(0);
        if (T < NT - 2) {
            asm volatile("s_waitcnt vmcnt(4)" ::: "memory");  // tile T+1 fully landed
            __builtin_amdgcn_s_barrier();
        } else if (T == NT - 2) {
            asm volatile("s_waitcnt vmcnt(0)" ::: "memory");  // last tile's stages (issued >=2 phases ago)
            __builtin_amdgcn_s_barrier();
        }
    }

    // epilogue: C/D 16x16 layout: col = lane&15, row = fq*4 + reg
    // acc[q*4+mf][qn*2+nf] -> row rowA0+wr*128+q*64+mf*16+fq*4+j, col rowB0+wc*64+qn*32+nf*16+frow
    #pragma unroll
    for (int mi = 0; mi < 8; ++mi) {
        #pragma unroll
        for (int j = 0; j < 4; ++j) {
            const int gm = rowA0 + wr * 128 + (mi >> 2) * 64 + (mi & 3) * 16 + fq * 4 + j;
            const float sc = inv_row[gm];
            #pragma unroll
            for (int cn = 0; cn < 4; ++cn) {
                const int gn = rowB0 + wc * 64 + (cn >> 1) * 32 + (cn & 1) * 16 + frow;
                out[(size_t)gm * N_TOT + gn] = acc[mi][cn][j] * sc + bias[gn];
            }
        }
    }
}

extern "C" void kernel_launch(void* const* d_in, const int* in_sizes, int n_in,
                              void* d_out, int out_size, void* d_ws, size_t ws_size,
                              hipStream_t stream) {
    const float* x = (const float*)d_in[0];
    const int* packed = (const int*)d_in[1];
    const float* wscale = (const float*)d_in[2];
    const float* bias = (const float*)d_in[3];
    float* out = (float*)d_out;

    uint16_t* q = (uint16_t*)d_ws;                                         // 64 MiB
    uint16_t* wt = (uint16_t*)((char*)d_ws + (size_t)M_TOT * K_TOT * 2);   // 2 MiB
    float* inv_row = (float*)((char*)d_ws + (size_t)M_TOT * K_TOT * 2 + (size_t)N_TOT * K_TOT * 2);

    quant_kernel<<<M_TOT, 256, 0, stream>>>(x, wscale, q, inv_row);
    unpack_kernel<<<OUT_F, 256, 0, stream>>>(packed, wt);
    gemm_kernel<<<(M_TOT / BM) * (N_TOT / BN), 512, 0, stream>>>(q, wt, inv_row, bias, out);
}

// Round 5
// 86.786 us; speedup vs baseline: 1.7027x; 1.3135x over previous
//
#include <hip/hip_runtime.h>
#include <hip/hip_bf16.h>
#include <stdint.h>

typedef int i32x4 __attribute__((ext_vector_type(4)));

constexpr int IN_F = 1024;
constexpr int OUT_F = 1024;
constexpr int M_TOT = 8 * 4096;   // 32768 tokens
constexpr int K_TOT = IN_F;
constexpr int N_TOT = OUT_F;

// ---------------- kernel 1: per-token int8 fake-quant -> int8 q ----------------
__global__ __launch_bounds__(256) void quant_kernel(
    const float* __restrict__ x,
    const float* __restrict__ wscale,
    int8_t* __restrict__ q,            // [M_TOT][K_TOT] int8
    float* __restrict__ inv_row)       // [M_TOT]  (= a/127 * weight_scale)
{
    const int row = blockIdx.x;
    const int t = threadIdx.x;
    const float4 v = reinterpret_cast<const float4*>(x + (size_t)row * IN_F)[t];
    float m = fmaxf(fmaxf(fabsf(v.x), fabsf(v.y)), fmaxf(fabsf(v.z), fabsf(v.w)));
    #pragma unroll
    for (int off = 32; off > 0; off >>= 1)
        m = fmaxf(m, __shfl_xor(m, off));
    __shared__ float smax[4];
    if ((t & 63) == 0) smax[t >> 6] = m;
    __syncthreads();
    m = fmaxf(fmaxf(smax[0], smax[1]), fmaxf(smax[2], smax[3]));
    const float a = fmaxf(m, 1e-5f);
    const float as = 127.0f / a;

    char4 o;
    o.x = (char)(int)fminf(fmaxf(rintf(v.x * as), -128.0f), 127.0f);
    o.y = (char)(int)fminf(fmaxf(rintf(v.y * as), -128.0f), 127.0f);
    o.z = (char)(int)fminf(fmaxf(rintf(v.z * as), -128.0f), 127.0f);
    o.w = (char)(int)fminf(fmaxf(rintf(v.w * as), -128.0f), 127.0f);
    reinterpret_cast<char4*>(q + (size_t)row * IN_F)[t] = o;
    if (t == 0) inv_row[row] = (a / 127.0f) * wscale[0];
}

// ---------------- kernel 2: unpack ternary weights (bit-plane permuted) -> int8 ----------------
__global__ __launch_bounds__(256) void unpack_kernel(
    const int* __restrict__ packed,
    int8_t* __restrict__ wt)           // [OUT_F][IN_F] int8 in {-1,0,1} (B^T layout)
{
    const int o = blockIdx.x;
    const int k0 = threadIdx.x * 4;
    const int sh = (o >> 8) * 2;
    const int pbase = ((o & 255) << 10) + k0;
    const int4 pw = *reinterpret_cast<const int4*>(packed + pbase);
    char4 r;
    r.x = (char)(((pw.x >> sh) & 3) - 1);
    r.y = (char)(((pw.y >> sh) & 3) - 1);
    r.z = (char)(((pw.z >> sh) & 3) - 1);
    r.w = (char)(((pw.w >> sh) & 3) - 1);
    *reinterpret_cast<char4*>(wt + (size_t)o * IN_F + k0) = r;
}

// ---------------- kernel 3: int8 MFMA GEMM (exact), 256x256 tile, BK=128 ----------------
// mfma_i32_16x16x64_i8. 8 waves (2M x 4N), per-wave 128x64 output.
// 2 phases / K-tile: Ph0 = rows-lo x all cols (reads A-R0 8 + B 8, b128), Ph1 = rows-hi
// (reads A-R1 8); B frags register-held across both phases. 32 MFMA per burst.
// LDS 128 KiB = [buf2][ab2][region2][128x128 i8]. All stages -> nxt buf (clean dbuf).
// A regions: R0 = rows {0-63}u{128-191}, R1 = {64-127}u{192-255} (Ph0/Ph1 rows of both
// wave-halves). B regions: n 0-127 / 128-255. Counted vmcnt(4)@Ph0-end (certifies A-R1),
// vmcnt(2)@Ph1-end (certifies B + A-R0 of next tile). Never 0 mid-loop.
// T2 swizzle: linear LDS dest, inverse-swizzled global src, swizzled ds_read (2-way free).
constexpr int BM = 256, BN = 256, BK = 128;
constexpr int NT = K_TOT / BK;   // 8

__global__ __launch_bounds__(512, 2) void gemm_kernel(
    const int8_t* __restrict__ qa,     // [M_TOT][K_TOT] int8
    const int8_t* __restrict__ wb,     // [N_TOT][K_TOT] int8
    const float* __restrict__ inv_row,
    const float* __restrict__ bias,
    float* __restrict__ out)
{
    // XCD-aware swizzle: nwg = 512, divisible by 8 -> bijective simple remap
    int bid = blockIdx.x;
    bid = (bid & 7) * ((int)gridDim.x >> 3) + (bid >> 3);
    const int tm = bid >> 2;            // 0..127
    const int tn = bid & 3;             // 0..3

    const int tid = threadIdx.x;
    const int lane = tid & 63;
    const int wid = tid >> 6;           // 0..7
    const int wr = wid >> 2;            // 0..1 (M half: rows wr*128..)
    const int wc = wid & 3;             // 0..3 (N quarter: cols wc*64..)

    __shared__ int8_t lds[2][2][2][128 * 128];  // [buf][ab][region] 16 KiB each = 128 KiB

    const int rowA0 = tm * BM;
    const int rowB0 = tn * BN;
    const int frow = lane & 15;
    const int fq = lane >> 4;           // 0..3

    i32x4 acc[8][4] = {};

    // stage one 16 KiB region (128 local rows x 128 k): 2 global_load_lds per thread
    auto stage = [&](int buf, int ab, int region, int kt) {
        const int8_t* base = ab ? wb : qa;
        #pragma unroll
        for (int j = 0; j < 2; ++j) {
            const int c = j * 512 + tid;          // chunk 0..1023 (16B each)
            const int rl = c >> 3, cc = c & 7;
            const int grow = ab ? (rowB0 + region * 128 + rl)
                                : (rowA0 + (rl & 64) * 2 + region * 64 + (rl & 63));
            const int scc = cc ^ (rl & 7);        // inverse swizzle on global src
            const int8_t* src = base + (size_t)grow * K_TOT + kt * BK + scc * 16;
            __builtin_amdgcn_global_load_lds(
                (const __attribute__((address_space(1))) void*)src,
                (__attribute__((address_space(3))) void*)&lds[buf][ab][region][c * 16],
                16, 0, 0);
        }
    };

    auto ldA = [&](int buf, int region, int mf, int ks) -> i32x4 {
        const int local = wr * 64 + (mf & 3) * 16 + frow;
        const int ch = (ks * 4 + fq) ^ (local & 7);
        return *reinterpret_cast<const i32x4*>(&lds[buf][0][region][local * 128 + ch * 16]);
    };
    auto ldB = [&](int buf, int nf, int ks) -> i32x4 {
        const int region = wc >> 1;
        const int local = (wc & 1) * 64 + nf * 16 + frow;
        const int ch = (ks * 4 + fq) ^ (local & 7);
        return *reinterpret_cast<const i32x4*>(&lds[buf][1][region][local * 128 + ch * 16]);
    };

    // prologue: stage tile 0 fully (8 loads), drain, barrier
    stage(0, 1, 0, 0); stage(0, 1, 1, 0); stage(0, 0, 0, 0); stage(0, 0, 1, 0);
    asm volatile("s_waitcnt vmcnt(0)" ::: "memory");
    __builtin_amdgcn_s_barrier();

    for (int T = 0; T < NT; ++T) {
        const int cur = T & 1, nxt = cur ^ 1;
        const bool st = (T + 1 < NT);
        i32x4 aF[4][2], bF[4][2];

        // ---- Ph0: read A-R0 (8) + B-all (8); stage nxt B-R0,B-R1; MFMA rows-lo (32)
        #pragma unroll
        for (int mf = 0; mf < 4; ++mf)
            #pragma unroll
            for (int ks = 0; ks < 2; ++ks)
                aF[mf][ks] = ldA(cur, 0, mf, ks);
        #pragma unroll
        for (int nf = 0; nf < 4; ++nf)
            #pragma unroll
            for (int ks = 0; ks < 2; ++ks)
                bF[nf][ks] = ldB(cur, nf, ks);
        if (st) { stage(nxt, 1, 0, T + 1); stage(nxt, 1, 1, T + 1); }
        __builtin_amdgcn_s_barrier();
        asm volatile("s_waitcnt lgkmcnt(0)" ::: "memory");
        __builtin_amdgcn_sched_barrier(0);
        __builtin_amdgcn_s_setprio(1);
        #pragma unroll
        for (int mf = 0; mf < 4; ++mf)
            #pragma unroll
            for (int nf = 0; nf < 4; ++nf)
                #pragma unroll
                for (int ks = 0; ks < 2; ++ks)
                    acc[mf][nf] = __builtin_amdgcn_mfma_i32_16x16x64_i8(
                        aF[mf][ks], bF[nf][ks], acc[mf][nf], 0, 0, 0);
        __builtin_amdgcn_s_setprio(0);
        if (st) asm volatile("s_waitcnt vmcnt(4)" ::: "memory");  // A-R1(T) certified
        else    asm volatile("s_waitcnt vmcnt(0)" ::: "memory");
        __builtin_amdgcn_s_barrier();

        // ---- Ph1: read A-R1 (8); stage nxt A-R0,A-R1; MFMA rows-hi (32)
        #pragma unroll
        for (int mf = 0; mf < 4; ++mf)
            #pragma unroll
            for (int ks = 0; ks < 2; ++ks)
                aF[mf][ks] = ldA(cur, 1, mf, ks);
        if (st) { stage(nxt, 0, 0, T + 1); stage(nxt, 0, 1, T + 1); }
        __builtin_amdgcn_s_barrier();
        asm volatile("s_waitcnt lgkmcnt(0)" ::: "memory");
        __builtin_amdgcn_sched_barrier(0);
        __builtin_amdgcn_s_setprio(1);
        #pragma unroll
        for (int mf = 0; mf < 4; ++mf)
            #pragma unroll
            for (int nf = 0; nf < 4; ++nf)
                #pragma unroll
                for (int ks = 0; ks < 2; ++ks)
                    acc[4 + mf][nf] = __builtin_amdgcn_mfma_i32_16x16x64_i8(
                        aF[mf][ks], bF[nf][ks], acc[4 + mf][nf], 0, 0, 0);
        __builtin_amdgcn_s_setprio(0);
        asm volatile("s_waitcnt vmcnt(2)" ::: "memory");  // B(T+1) + A-R0(T+1) certified
        __builtin_amdgcn_s_barrier();
    }

    // epilogue: C/D 16x16 layout: col = lane&15, row = fq*4 + reg. acc exact in i32.
    #pragma unroll
    for (int mi = 0; mi < 8; ++mi) {
        #pragma unroll
        for (int j = 0; j < 4; ++j) {
            const int gm = rowA0 + wr * 128 + mi * 16 + fq * 4 + j;
            const float sc = inv_row[gm];
            #pragma unroll
            for (int nf = 0; nf < 4; ++nf) {
                const int gn = rowB0 + wc * 64 + nf * 16 + frow;
                out[(size_t)gm * N_TOT + gn] = (float)acc[mi][nf][j] * sc + bias[gn];
            }
        }
    }
}

extern "C" void kernel_launch(void* const* d_in, const int* in_sizes, int n_in,
                              void* d_out, int out_size, void* d_ws, size_t ws_size,
                              hipStream_t stream) {
    const float* x = (const float*)d_in[0];
    const int* packed = (const int*)d_in[1];
    const float* wscale = (const float*)d_in[2];
    const float* bias = (const float*)d_in[3];
    float* out = (float*)d_out;

    int8_t* q = (int8_t*)d_ws;                                          // 32 MiB
    int8_t* wt = (int8_t*)((char*)d_ws + (size_t)M_TOT * K_TOT);        // 1 MiB
    float* inv_row = (float*)((char*)d_ws + (size_t)M_TOT * K_TOT + (size_t)N_TOT * K_TOT);

    quant_kernel<<<M_TOT, 256, 0, stream>>>(x, wscale, q, inv_row);
    unpack_kernel<<<OUT_F, 256, 0, stream>>>(packed, wt);
    gemm_kernel<<<(M_TOT / BM) * (N_TOT / BN), 512, 0, stream>>>(q, wt, inv_row, bias, out);
}